// Round 1
// baseline (9307.448 us; speedup 1.0000x reference)
//
#include <hip/hip_runtime.h>
#include <math.h>

#define GS 1024
#define FEAT 32

__device__ __forceinline__ void bilerp32(const float* __restrict__ g,
                                         float c0, float c1,
                                         float lo0, float hi0,
                                         float lo1, float hi1,
                                         float* __restrict__ xout)
{
    // Reference: x from coord0 scaled by (gs0-1), y from coord1 scaled by (gs1-1),
    // grid indexed [y, x]. trunc == floor (non-negative).
    float fx = (c0 - lo0) / (hi0 - lo0) * 1023.0f;
    float fy = (c1 - lo1) / (hi1 - lo1) * 1023.0f;
    int x0 = (int)fx;
    int y0 = (int)fy;
    float xf = fx - (float)x0;   // == fx % 1.0 for non-negative fx
    float yf = fy - (float)y0;
    x0 = min(max(x0, 0), GS - 1);
    y0 = min(max(y0, 0), GS - 1);
    int x1 = min(x0 + 1, GS - 1);
    int y1 = min(y0 + 1, GS - 1);

    float w00 = (1.0f - xf) * (1.0f - yf);  // tl
    float w10 = xf * (1.0f - yf);           // tr
    float w01 = (1.0f - xf) * yf;           // bl
    float w11 = xf * yf;                    // br

    const float4* tl = (const float4*)(g + ((size_t)y0 * GS + x0) * FEAT);
    const float4* tr = (const float4*)(g + ((size_t)y0 * GS + x1) * FEAT);
    const float4* bl = (const float4*)(g + ((size_t)y1 * GS + x0) * FEAT);
    const float4* br = (const float4*)(g + ((size_t)y1 * GS + x1) * FEAT);

#pragma unroll
    for (int fb = 0; fb < FEAT / 4; ++fb) {
        float4 a = tl[fb];
        float4 b = tr[fb];
        float4 c = bl[fb];
        float4 d = br[fb];
        xout[fb * 4 + 0] = w00 * a.x + w10 * b.x + w01 * c.x + w11 * d.x;
        xout[fb * 4 + 1] = w00 * a.y + w10 * b.y + w01 * c.y + w11 * d.y;
        xout[fb * 4 + 2] = w00 * a.z + w10 * b.z + w01 * c.z + w11 * d.z;
        xout[fb * 4 + 3] = w00 * a.w + w10 * b.w + w01 * c.w + w11 * d.w;
    }
}

__global__ __launch_bounds__(256, 4) void gridnet_kernel(
    const float* __restrict__ pos,      // [N,2]
    const float* __restrict__ dir,      // [N,2]
    const float* __restrict__ grid_pos, // [1024,1024,32]
    const float* __restrict__ grid_dir, // [1024,1024,32]
    const float* __restrict__ W1,       // [64,128]
    const float* __restrict__ b1,       // [128]
    const float* __restrict__ W2,       // [128,3]
    const float* __restrict__ b2,       // [3]
    float* __restrict__ out,            // [N,3]
    int n)
{
    const int i = blockIdx.x * blockDim.x + threadIdx.x;
    if (i >= n) return;

    const float PI = 3.14159265358979323846f;

    float x[64];
    // pos -> x[0..31], range ((0,pi),(-pi,pi))
    {
        float p0 = pos[2 * i + 0];
        float p1 = pos[2 * i + 1];
        bilerp32(grid_pos, p0, p1, 0.0f, PI, -PI, PI, &x[0]);
    }
    // dir -> x[32..63]
    {
        float d0 = dir[2 * i + 0];
        float d1 = dir[2 * i + 1];
        bilerp32(grid_dir, d0, d1, 0.0f, PI, -PI, PI, &x[32]);
    }

    // out accumulators (seed with b2)
    float o0 = b2[0], o1 = b2[1], o2 = b2[2];

    // h = leaky_relu(x @ W1 + b1); out += h @ W2  -- j-blocked by 16
    for (int j0 = 0; j0 < 128; j0 += 16) {
        float acc[16];
#pragma unroll
        for (int jj = 0; jj < 16; ++jj) acc[jj] = b1[j0 + jj];

#pragma unroll
        for (int k = 0; k < 64; ++k) {
            float xk = x[k];
            const float* __restrict__ wrow = W1 + k * 128 + j0;  // uniform -> s_load
#pragma unroll
            for (int jj = 0; jj < 16; ++jj)
                acc[jj] = fmaf(xk, wrow[jj], acc[jj]);
        }

#pragma unroll
        for (int jj = 0; jj < 16; ++jj) {
            float h = acc[jj];
            h = (h > 0.0f) ? h : 0.01f * h;           // leaky_relu slope 0.01
            const float* __restrict__ w2r = W2 + (j0 + jj) * 3;  // uniform -> s_load
            o0 = fmaf(h, w2r[0], o0);
            o1 = fmaf(h, w2r[1], o1);
            o2 = fmaf(h, w2r[2], o2);
        }
    }

    // sigmoid * 255
    out[i * 3 + 0] = 255.0f / (1.0f + expf(-o0));
    out[i * 3 + 1] = 255.0f / (1.0f + expf(-o1));
    out[i * 3 + 2] = 255.0f / (1.0f + expf(-o2));
}

extern "C" void kernel_launch(void* const* d_in, const int* in_sizes, int n_in,
                              void* d_out, int out_size, void* d_ws, size_t ws_size,
                              hipStream_t stream) {
    const float* pos      = (const float*)d_in[0];
    const float* dir      = (const float*)d_in[1];
    const float* grid_pos = (const float*)d_in[2];
    const float* grid_dir = (const float*)d_in[3];
    const float* W1       = (const float*)d_in[4];
    const float* b1       = (const float*)d_in[5];
    const float* W2       = (const float*)d_in[6];
    const float* b2       = (const float*)d_in[7];
    float* out            = (float*)d_out;

    const int n = in_sizes[0] / 2;  // pos is [N,2]
    const int block = 256;
    const int grid = (n + block - 1) / block;

    gridnet_kernel<<<grid, block, 0, stream>>>(pos, dir, grid_pos, grid_dir,
                                               W1, b1, W2, b2, out, n);
}

// Round 2
// 1109.552 us; speedup vs baseline: 8.3885x; 8.3885x over previous
//
#include <hip/hip_runtime.h>
#include <math.h>

#define GS 1024
#define FEAT 32

__device__ __forceinline__ void bilerp32(const float* __restrict__ g,
                                         float c0, float c1,
                                         float lo0, float hi0,
                                         float lo1, float hi1,
                                         float* __restrict__ xout)
{
    float fx = (c0 - lo0) / (hi0 - lo0) * 1023.0f;
    float fy = (c1 - lo1) / (hi1 - lo1) * 1023.0f;
    int x0 = (int)fx;
    int y0 = (int)fy;
    float xf = fx - (float)x0;
    float yf = fy - (float)y0;
    x0 = min(max(x0, 0), GS - 1);
    y0 = min(max(y0, 0), GS - 1);
    int x1 = min(x0 + 1, GS - 1);
    int y1 = min(y0 + 1, GS - 1);

    float w00 = (1.0f - xf) * (1.0f - yf);
    float w10 = xf * (1.0f - yf);
    float w01 = (1.0f - xf) * yf;
    float w11 = xf * yf;

    const float4* tl = (const float4*)(g + ((size_t)y0 * GS + x0) * FEAT);
    const float4* tr = (const float4*)(g + ((size_t)y0 * GS + x1) * FEAT);
    const float4* bl = (const float4*)(g + ((size_t)y1 * GS + x0) * FEAT);
    const float4* br = (const float4*)(g + ((size_t)y1 * GS + x1) * FEAT);

#pragma unroll
    for (int fb = 0; fb < FEAT / 4; ++fb) {
        float4 a = tl[fb];
        float4 b = tr[fb];
        float4 c = bl[fb];
        float4 d = br[fb];
        xout[fb * 4 + 0] = w00 * a.x + w10 * b.x + w01 * c.x + w11 * d.x;
        xout[fb * 4 + 1] = w00 * a.y + w10 * b.y + w01 * c.y + w11 * d.y;
        xout[fb * 4 + 2] = w00 * a.z + w10 * b.z + w01 * c.z + w11 * d.z;
        xout[fb * 4 + 3] = w00 * a.w + w10 * b.w + w01 * c.w + w11 * d.w;
    }
}

// (256, 2): min 2 waves/EU -> VGPR cap 256. Round-1 failure: default/(256,4)
// capped at 128, allocator spilled x[64]+acc[16] to scratch (WRITE_SIZE 2.9GB).
__global__ __launch_bounds__(256, 2) void gridnet_kernel(
    const float* __restrict__ pos,
    const float* __restrict__ dir,
    const float* __restrict__ grid_pos,
    const float* __restrict__ grid_dir,
    const float* __restrict__ W1,       // [64,128]
    const float* __restrict__ b1,       // [128]
    const float* __restrict__ W2,       // [128,3]
    const float* __restrict__ b2,       // [3]
    float* __restrict__ out,            // [N,3]
    int n)
{
    const int i = blockIdx.x * blockDim.x + threadIdx.x;
    if (i >= n) return;

    const float PI = 3.14159265358979323846f;

    float x[64];
    {
        float p0 = pos[2 * i + 0];
        float p1 = pos[2 * i + 1];
        bilerp32(grid_pos, p0, p1, 0.0f, PI, -PI, PI, &x[0]);
    }
    {
        float d0 = dir[2 * i + 0];
        float d1 = dir[2 * i + 1];
        bilerp32(grid_dir, d0, d1, 0.0f, PI, -PI, PI, &x[32]);
    }

    float o0 = b2[0], o1 = b2[1], o2 = b2[2];

    for (int j0 = 0; j0 < 128; j0 += 16) {
        float acc[16];
#pragma unroll
        for (int jj = 0; jj < 16; ++jj) acc[jj] = b1[j0 + jj];

#pragma unroll
        for (int k = 0; k < 64; ++k) {
            float xk = x[k];
            const float* __restrict__ wrow = W1 + k * 128 + j0;  // uniform addr
#pragma unroll
            for (int jj = 0; jj < 16; ++jj)
                acc[jj] = fmaf(xk, wrow[jj], acc[jj]);
        }

#pragma unroll
        for (int jj = 0; jj < 16; ++jj) {
            float h = acc[jj];
            h = (h > 0.0f) ? h : 0.01f * h;
            const float* __restrict__ w2r = W2 + (j0 + jj) * 3;  // uniform addr
            o0 = fmaf(h, w2r[0], o0);
            o1 = fmaf(h, w2r[1], o1);
            o2 = fmaf(h, w2r[2], o2);
        }
    }

    // sigmoid*255 via hw exp2 + rcp (approx ok: tolerance passed at absmax 1.0)
    const float NLOG2E = -1.4426950408889634f;
    float s0 = 255.0f * __builtin_amdgcn_rcpf(1.0f + __builtin_amdgcn_exp2f(o0 * NLOG2E));
    float s1 = 255.0f * __builtin_amdgcn_rcpf(1.0f + __builtin_amdgcn_exp2f(o1 * NLOG2E));
    float s2 = 255.0f * __builtin_amdgcn_rcpf(1.0f + __builtin_amdgcn_exp2f(o2 * NLOG2E));

    out[i * 3 + 0] = s0;
    out[i * 3 + 1] = s1;
    out[i * 3 + 2] = s2;
}

extern "C" void kernel_launch(void* const* d_in, const int* in_sizes, int n_in,
                              void* d_out, int out_size, void* d_ws, size_t ws_size,
                              hipStream_t stream) {
    const float* pos      = (const float*)d_in[0];
    const float* dir      = (const float*)d_in[1];
    const float* grid_pos = (const float*)d_in[2];
    const float* grid_dir = (const float*)d_in[3];
    const float* W1       = (const float*)d_in[4];
    const float* b1       = (const float*)d_in[5];
    const float* W2       = (const float*)d_in[6];
    const float* b2       = (const float*)d_in[7];
    float* out            = (float*)d_out;

    const int n = in_sizes[0] / 2;
    const int block = 256;
    const int grid = (n + block - 1) / block;

    gridnet_kernel<<<grid, block, 0, stream>>>(pos, dir, grid_pos, grid_dir,
                                               W1, b1, W2, b2, out, n);
}

// Round 3
// 540.279 us; speedup vs baseline: 17.2271x; 2.0537x over previous
//
#include <hip/hip_runtime.h>
#include <math.h>

#define GS 1024

typedef __attribute__((ext_vector_type(8))) short short8;   // 8 x bf16 fragment
typedef __attribute__((ext_vector_type(4))) float f32x4;

__device__ __forceinline__ unsigned short f2bf(float f) {
    // RNE float -> bf16
    unsigned int u = __float_as_uint(f);
    return (unsigned short)((u + 0x7fffu + ((u >> 16) & 1u)) >> 16);
}

// Gather 8 bilerped features (slice f0..f0+7) of one point into a bf16 A-fragment slice.
__device__ __forceinline__ short8 gather8(const float* __restrict__ g,
                                          float c0, float c1, int f0)
{
    const float S0 = 325.6307907984f;   // 1023/pi
    const float S1 = 162.8153953992f;   // 1023/(2pi)
    const float PI = 3.14159265358979323846f;
    float fx = c0 * S0;
    float fy = (c1 + PI) * S1;
    int x0 = (int)fx, y0 = (int)fy;
    float xf = fx - (float)x0;
    float yf = fy - (float)y0;
    x0 = min(max(x0, 0), GS - 1);
    y0 = min(max(y0, 0), GS - 1);
    int x1 = min(x0 + 1, GS - 1);
    int y1 = min(y0 + 1, GS - 1);
    float w00 = (1.0f - xf) * (1.0f - yf);
    float w10 = xf * (1.0f - yf);
    float w01 = (1.0f - xf) * yf;
    float w11 = xf * yf;
    const f32x4* tl = (const f32x4*)(g + ((size_t)(y0 * GS + x0) * 32 + f0));
    const f32x4* tr = (const f32x4*)(g + ((size_t)(y0 * GS + x1) * 32 + f0));
    const f32x4* bl = (const f32x4*)(g + ((size_t)(y1 * GS + x0) * 32 + f0));
    const f32x4* br = (const f32x4*)(g + ((size_t)(y1 * GS + x1) * 32 + f0));
    f32x4 a0 = tl[0], a1 = tl[1];
    f32x4 b0 = tr[0], b1v = tr[1];
    f32x4 c0v = bl[0], c1v = bl[1];
    f32x4 d0 = br[0], d1 = br[1];
    short8 r;
#pragma unroll
    for (int e = 0; e < 4; ++e) {
        float v = w00 * a0[e] + w10 * b0[e] + w01 * c0v[e] + w11 * d0[e];
        r[e] = (short)f2bf(v);
    }
#pragma unroll
    for (int e = 0; e < 4; ++e) {
        float v = w00 * a1[e] + w10 * b1v[e] + w01 * c1v[e] + w11 * d1[e];
        r[4 + e] = (short)f2bf(v);
    }
    return r;
}

// 1 wave = 64 points. A built gather-direct (lane: point=l&15 (+16*mt), k-slice=(l>>4)*8).
// B from LDS W1^T bf16, row-padded +16B (stride 72 elems) to break the stride-128B conflict.
// A and B share the same (group,elem)->k convention => HW k-permutation cancels.
__global__ __launch_bounds__(256, 2) void gridnet_kernel(
    const float* __restrict__ pos,
    const float* __restrict__ dir,
    const float* __restrict__ gpos,
    const float* __restrict__ gdir,
    const float* __restrict__ W1,   // [64,128]
    const float* __restrict__ b1,   // [128]
    const float* __restrict__ W2,   // [128,3]
    const float* __restrict__ b2,   // [3]
    float* __restrict__ out,        // [N,3]
    int n)
{
    __shared__ unsigned short w1t[128 * 72];  // [col][k] bf16, padded: 18KB
    __shared__ float w2s[128 * 3];
    __shared__ float b1s[128];

    const int tid  = threadIdx.x;
    const int lane = tid & 63;
    const int wave = tid >> 6;
    const int lrow = lane & 15;   // point-in-mtile / col-in-ntile
    const int lgrp = lane >> 4;   // k-slice group
    const int f0   = lgrp * 8;

    // ---- one-time stage: W1^T bf16, W2, b1 ----
    for (int idx = tid; idx < 8192; idx += 256) {
        int col = idx & 127, k = idx >> 7;
        w1t[col * 72 + k] = f2bf(W1[k * 128 + col]);   // read = W1[idx], coalesced
    }
    if (tid < 128) {
        b1s[tid] = b1[tid];
        w2s[tid * 3 + 0] = W2[tid * 3 + 0];
        w2s[tid * 3 + 1] = W2[tid * 3 + 1];
        w2s[tid * 3 + 2] = W2[tid * 3 + 2];
    }
    __syncthreads();

    const int base = blockIdx.x * 256 + wave * 64;

    // ---- gather A fragments: [mt][kt], kt0=pos-grid feats 0-31, kt1=dir-grid ----
    short8 afrag[4][2];
#pragma unroll
    for (int mt = 0; mt < 4; ++mt) {
        int gi = min(base + mt * 16 + lrow, n - 1);
        float p0 = pos[2 * gi], p1 = pos[2 * gi + 1];
        float d0 = dir[2 * gi], d1 = dir[2 * gi + 1];
        afrag[mt][0] = gather8(gpos, p0, p1, f0);
        afrag[mt][1] = gather8(gdir, d0, d1, f0);
    }

    // ---- layer1 MFMA + fused layer2 partials ----
    float opart[48];   // [combo=mt*4+reg][3]
#pragma unroll
    for (int v = 0; v < 48; ++v) opart[v] = 0.0f;

#pragma unroll
    for (int nt = 0; nt < 8; ++nt) {
        const int col = nt * 16 + lrow;
        short8 bf0 = *(const short8*)&w1t[col * 72 + f0];        // k = 0..31 slice
        short8 bf1 = *(const short8*)&w1t[col * 72 + 32 + f0];   // k = 32..63 slice

        f32x4 acc[4];
#pragma unroll
        for (int mt = 0; mt < 4; ++mt) acc[mt] = (f32x4){0.f, 0.f, 0.f, 0.f};
#pragma unroll
        for (int mt = 0; mt < 4; ++mt) {
            acc[mt] = __builtin_amdgcn_mfma_f32_16x16x32_bf16(afrag[mt][0], bf0, acc[mt], 0, 0, 0);
            acc[mt] = __builtin_amdgcn_mfma_f32_16x16x32_bf16(afrag[mt][1], bf1, acc[mt], 0, 0, 0);
        }

        float b1v = b1s[col];
        float wa = w2s[col * 3 + 0];
        float wb = w2s[col * 3 + 1];
        float wc = w2s[col * 3 + 2];
#pragma unroll
        for (int mt = 0; mt < 4; ++mt) {
#pragma unroll
            for (int r = 0; r < 4; ++r) {
                float h = acc[mt][r] + b1v;
                h = (h > 0.0f) ? h : 0.01f * h;
                opart[(mt * 4 + r) * 3 + 0] += h * wa;
                opart[(mt * 4 + r) * 3 + 1] += h * wb;
                opart[(mt * 4 + r) * 3 + 2] += h * wc;
            }
        }
    }

    // ---- reduce-scatter across the 16 lanes of each lgrp group (static indices only) ----
    float r8[24];
#pragma unroll
    for (int i = 0; i < 24; ++i) {
        float a = opart[i]      + __shfl_xor(opart[i],      8, 64);
        float b = opart[i + 24] + __shfl_xor(opart[i + 24], 8, 64);
        r8[i] = (lane & 8) ? b : a;
    }
    float r4[12];
#pragma unroll
    for (int i = 0; i < 12; ++i) {
        float a = r8[i]      + __shfl_xor(r8[i],      4, 64);
        float b = r8[i + 12] + __shfl_xor(r8[i + 12], 4, 64);
        r4[i] = (lane & 4) ? b : a;
    }
    float r2[6];
#pragma unroll
    for (int i = 0; i < 6; ++i) {
        float a = r4[i]     + __shfl_xor(r4[i],     2, 64);
        float b = r4[i + 6] + __shfl_xor(r4[i + 6], 2, 64);
        r2[i] = (lane & 2) ? b : a;
    }
    float r1[3];
#pragma unroll
    for (int i = 0; i < 3; ++i) {
        float a = r2[i]     + __shfl_xor(r2[i],     1, 64);
        float b = r2[i + 3] + __shfl_xor(r2[i + 3], 1, 64);
        r1[i] = (lane & 1) ? b : a;
    }

    // lane now owns combo idx == lrow -> point p (C/D row map: row = lgrp*4 + reg)
    const int p  = (lrow >> 2) * 16 + lgrp * 4 + (lrow & 3);
    const int gp = base + p;
    if (gp < n) {
        const float NLOG2E = -1.4426950408889634f;
#pragma unroll
        for (int c = 0; c < 3; ++c) {
            float o = r1[c] + b2[c];
            float s = 255.0f * __builtin_amdgcn_rcpf(1.0f + __builtin_amdgcn_exp2f(o * NLOG2E));
            out[gp * 3 + c] = s;
        }
    }
}

extern "C" void kernel_launch(void* const* d_in, const int* in_sizes, int n_in,
                              void* d_out, int out_size, void* d_ws, size_t ws_size,
                              hipStream_t stream) {
    const float* pos      = (const float*)d_in[0];
    const float* dir      = (const float*)d_in[1];
    const float* grid_pos = (const float*)d_in[2];
    const float* grid_dir = (const float*)d_in[3];
    const float* W1       = (const float*)d_in[4];
    const float* b1       = (const float*)d_in[5];
    const float* W2       = (const float*)d_in[6];
    const float* b2       = (const float*)d_in[7];
    float* out            = (float*)d_out;

    const int n = in_sizes[0] / 2;
    const int block = 256;               // 4 waves, 64 points each
    const int grid = (n + block - 1) / block;

    gridnet_kernel<<<grid, block, 0, stream>>>(pos, dir, grid_pos, grid_dir,
                                               W1, b1, W2, b2, out, n);
}